// Round 1
// baseline (186.219 us; speedup 1.0000x reference)
//
#include <hip/hip_runtime.h>

#define K_BASES 128
#define PATCH_NUM 196

__global__ __launch_bounds__(256) void patch_recon_kernel(
    const float* __restrict__ h_scores, // [B,128,3,14]
    const float* __restrict__ v_score,  // [B,128,3,14]
    const float* __restrict__ h_base,   // [B,128,16]
    const float* __restrict__ v_base,   // [B,128,16]
    float* __restrict__ out)            // [B,196,3,16,16]
{
    __shared__ float vb[K_BASES * 16];   // v_base tile (m index)
    __shared__ float hb[K_BASES * 16];   // h_base tile (n index)
    __shared__ float sc[3][K_BASES];     // raw scores
    __shared__ float w[3][K_BASES];      // softmax weights

    const int bp  = blockIdx.x;
    const int b   = bp / PATCH_NUM;
    const int p   = bp % PATCH_NUM;
    const int np_ = p / 14;  // indexes h_scores last dim (n')
    const int mp_ = p % 14;  // indexes v_score  last dim (m')
    const int tid = threadIdx.x;

    // ---- stage base vectors (coalesced, 2048 floats each) ----
    const float* hbg = h_base + (size_t)b * K_BASES * 16;
    const float* vbg = v_base + (size_t)b * K_BASES * 16;
#pragma unroll
    for (int i = 0; i < 8; ++i) {
        hb[tid + i * 256] = hbg[tid + i * 256];
        vb[tid + i * 256] = vbg[tid + i * 256];
    }

    // ---- raw scores: 3 channels x 128 bases ----
    for (int idx = tid; idx < 3 * K_BASES; idx += 256) {
        int c = idx >> 7, k = idx & 127;
        float hs = h_scores[(((size_t)b * K_BASES + k) * 3 + c) * 14 + np_];
        float vs = v_score [(((size_t)b * K_BASES + k) * 3 + c) * 14 + mp_];
        sc[c][k] = hs * vs;
    }
    __syncthreads();

    // ---- softmax over k per channel: one wave per channel ----
    const int wave = tid >> 6, lane = tid & 63;
    if (wave < 3) {
        const int c = wave;
        float s0 = sc[c][lane], s1 = sc[c][lane + 64];
        float mx = fmaxf(s0, s1);
#pragma unroll
        for (int off = 32; off; off >>= 1) mx = fmaxf(mx, __shfl_xor(mx, off));
        float e0 = __expf(s0 - mx), e1 = __expf(s1 - mx);
        float sum = e0 + e1;
#pragma unroll
        for (int off = 32; off; off >>= 1) sum += __shfl_xor(sum, off);
        float inv = 1.0f / sum;
        w[c][lane]      = e0 * inv;
        w[c][lane + 64] = e1 * inv;
    }
    __syncthreads();

    // ---- weighted sum of rank-1 base images ----
    // thread t owns output element (m = t>>4, n = t&15); n contiguous -> coalesced stores
    const int n = tid & 15, m = tid >> 4;
    float acc0 = 0.f, acc1 = 0.f, acc2 = 0.f;
#pragma unroll 4
    for (int k = 0; k < K_BASES; ++k) {
        float prod = vb[k * 16 + m] * hb[k * 16 + n];   // base_matrix[k][m][n]
        acc0 = fmaf(w[0][k], prod, acc0);
        acc1 = fmaf(w[1][k], prod, acc1);
        acc2 = fmaf(w[2][k], prod, acc2);
    }

    float* o = out + (size_t)bp * 768 + tid;  // ((b*196+p)*3+c)*256 + m*16+n
    o[0]   = acc0;
    o[256] = acc1;
    o[512] = acc2;
}

extern "C" void kernel_launch(void* const* d_in, const int* in_sizes, int n_in,
                              void* d_out, int out_size, void* d_ws, size_t ws_size,
                              hipStream_t stream) {
    const float* h_scores = (const float*)d_in[0];
    const float* v_score  = (const float*)d_in[1];
    const float* h_base   = (const float*)d_in[2];
    const float* v_base   = (const float*)d_in[3];
    float* out = (float*)d_out;

    const int B = in_sizes[0] / (K_BASES * 3 * 14);
    dim3 grid(B * PATCH_NUM);
    dim3 block(256);
    patch_recon_kernel<<<grid, block, 0, stream>>>(h_scores, v_score, h_base, v_base, out);
}

// Round 2
// 38.076 us; speedup vs baseline: 4.8907x; 4.8907x over previous
//
#include <hip/hip_runtime.h>

typedef __attribute__((ext_vector_type(8))) short bf16x8;
typedef __attribute__((ext_vector_type(4))) float f32x4;

#define PATCHES 196
#define ROWS 588           // 196 patches * 3 channels
#define NCHUNK 10          // ceil(588/64) row-chunks per batch
#define SCORE_B_STRIDE 5376  // 128*3*14 floats

// pack two f32 -> two bf16 (RNE) in one u32
static __device__ __forceinline__ unsigned f2bf2(float a, float b) {
    union { float f; unsigned u; } x, y; x.f = a; y.f = b;
    unsigned lo = (x.u + 0x7FFFu + ((x.u >> 16) & 1u)) >> 16;
    unsigned hi = (y.u + 0x7FFFu + ((y.u >> 16) & 1u)) & 0xFFFF0000u;
    return lo | hi;
}

// ---------------- Kernel 1: BM[b][mn][k] bf16 (k-contiguous) into workspace ----
__global__ __launch_bounds__(256) void bm_build(
    const float* __restrict__ h_base,   // [B,128,16]
    const float* __restrict__ v_base,   // [B,128,16]
    unsigned short* __restrict__ bm)    // [B,256,128] bf16
{
    __shared__ float hb[2048], vb[2048];
    const int b = blockIdx.x, t = threadIdx.x;
    const float* hg = h_base + (size_t)b * 2048;
    const float* vg = v_base + (size_t)b * 2048;
#pragma unroll
    for (int i = 0; i < 8; ++i) { hb[i*256+t] = hg[i*256+t]; vb[i*256+t] = vg[i*256+t]; }
    __syncthreads();

    const int m = t >> 4, n = t & 15;   // mn = t
    unsigned short* dst = bm + (size_t)b * 32768 + t * 128;
#pragma unroll
    for (int k0 = 0; k0 < 128; k0 += 8) {
        float p[8];
#pragma unroll
        for (int j = 0; j < 8; ++j)
            p[j] = vb[(k0+j)*16 + m] * hb[(k0+j)*16 + n];   // BM[k][mn]
        uint4 u = { f2bf2(p[0],p[1]), f2bf2(p[2],p[3]), f2bf2(p[4],p[5]), f2bf2(p[6],p[7]) };
        *(uint4*)(dst + k0) = u;
    }
}

// ---------------- Kernel 2: fused softmax-W + MFMA GEMM ------------------------
// LDS map: [0,16K)   W   [64 rows][128 k] bf16, XOR-swizzled
//          [16K,80K) BM  [256 mn][128 k] bf16, XOR-swizzled  (v_score staged here first)
__global__ __launch_bounds__(256) void patch_gemm(
    const float* __restrict__ h_scores, // [B,128,3,14]
    const float* __restrict__ v_score,  // [B,128,3,14]
    const unsigned short* __restrict__ bm,
    float* __restrict__ out)            // [B,196,3,16,16] == [B,588,256]
{
    __shared__ __align__(16) char lds[81920];

    const int bid = blockIdx.x;
    // bijective XCD grouping: all NCHUNK chunks of a batch land on XCD (b%8)
    const int xcd  = bid & 7;
    const int rest = bid >> 3;
    const int b     = (rest / NCHUNK) * 8 + xcd;
    const int chunk = rest % NCHUNK;
    const int t = threadIdx.x;

    // ---- stage v_score[b] (21504 B) into BM region (coalesced uint4) ----
    const uint4* vsg = (const uint4*)(v_score + (size_t)b * SCORE_B_STRIDE);
    uint4* vsl = (uint4*)(lds + 16384);
#pragma unroll
    for (int i = 0; i < 6; ++i) { int ci = t + i*256; if (ci < 1344) vsl[ci] = vsg[ci]; }
    __syncthreads();

    // ---- softmax weights: thread = (row r = t>>2, k-quarter kq = t&3) ----
    {
        const int r = t >> 2, kq = t & 3;
        const int grow = chunk * 64 + r;
        const bool valid = grow < ROWS;
        const int p = grow / 3, c = grow - p * 3;
        const int np = p / 14, mp = p - np * 14;
        const float* vs_l = (const float*)(lds + 16384);
        const float* hsb  = h_scores + (size_t)b * SCORE_B_STRIDE;
        const int vix = c * 14 + mp;
        const int hix = c * 14 + np;

        float sc[32];
#pragma unroll
        for (int j = 0; j < 32; ++j) {
            const int k = kq * 32 + j;
            float hsv = valid ? hsb[k * 42 + hix] : 0.f;
            sc[j] = hsv * vs_l[k * 42 + vix];
        }
        float mx = sc[0];
#pragma unroll
        for (int j = 1; j < 32; ++j) mx = fmaxf(mx, sc[j]);
        mx = fmaxf(mx, __shfl_xor(mx, 1));
        mx = fmaxf(mx, __shfl_xor(mx, 2));
        float sum = 0.f;
#pragma unroll
        for (int j = 0; j < 32; ++j) { sc[j] = __expf(sc[j] - mx); sum += sc[j]; }
        sum += __shfl_xor(sum, 1);
        sum += __shfl_xor(sum, 2);
        const float inv = 1.f / sum;

        const int sw = (r & 7) << 4;
#pragma unroll
        for (int s2 = 0; s2 < 4; ++s2) {
            const int k0 = kq * 32 + s2 * 8;
            uint4 u = { f2bf2(sc[s2*8+0]*inv, sc[s2*8+1]*inv),
                        f2bf2(sc[s2*8+2]*inv, sc[s2*8+3]*inv),
                        f2bf2(sc[s2*8+4]*inv, sc[s2*8+5]*inv),
                        f2bf2(sc[s2*8+6]*inv, sc[s2*8+7]*inv) };
            *(uint4*)(lds + r * 256 + ((k0 * 2) ^ sw)) = u;
        }
    }
    __syncthreads();

    // ---- stage BM[b] 64KB into LDS with XOR swizzle (overwrites v_score) ----
    {
        const uint4* bmg = (const uint4*)(bm + (size_t)b * 32768);
#pragma unroll
        for (int i = 0; i < 16; ++i) {
            const int ci = t + i * 256;          // 16B-chunk index, 0..4095
            uint4 v = bmg[ci];
            const int mn = ci >> 4, kb = (ci & 15) * 16;
            *(uint4*)(lds + 16384 + mn * 256 + (kb ^ ((mn & 7) << 4))) = v;
        }
    }
    __syncthreads();

    // ---- MFMA: wave (wm = w>>1 owns 2 M-tiles, wn = w&1 owns 8 N-tiles) ----
    const int w = t >> 6, lane = t & 63;
    const int wm = w >> 1, wn = w & 1;
    const int lr = lane & 15, lg = lane >> 4;

    bf16x8 afrag[2][4];
#pragma unroll
    for (int mi = 0; mi < 2; ++mi) {
        const int r2 = wm * 32 + mi * 16 + lr;
        const int sw = (r2 & 7) << 4;
#pragma unroll
        for (int kc = 0; kc < 4; ++kc)
            afrag[mi][kc] = *(const bf16x8*)(lds + r2 * 256 + ((kc * 64 + lg * 16) ^ sw));
    }

    f32x4 acc[2][8];
#pragma unroll
    for (int mi = 0; mi < 2; ++mi)
#pragma unroll
        for (int nt = 0; nt < 8; ++nt)
            acc[mi][nt] = (f32x4){0.f, 0.f, 0.f, 0.f};

#pragma unroll
    for (int nt = 0; nt < 8; ++nt) {
        const int mn = wn * 128 + nt * 16 + lr;
        const char* bmrow = lds + 16384 + mn * 256;
        const int sw = (mn & 7) << 4;
#pragma unroll
        for (int kc = 0; kc < 4; ++kc) {
            bf16x8 bfrag = *(const bf16x8*)(bmrow + ((kc * 64 + lg * 16) ^ sw));
            acc[0][nt] = __builtin_amdgcn_mfma_f32_16x16x32_bf16(afrag[0][kc], bfrag, acc[0][nt], 0, 0, 0);
            acc[1][nt] = __builtin_amdgcn_mfma_f32_16x16x32_bf16(afrag[1][kc], bfrag, acc[1][nt], 0, 0, 0);
        }
    }

    // ---- store: C/D layout col=lane&15, row=(lane>>4)*4+reg ----
    float* ob = out + (size_t)b * (ROWS * 256);
#pragma unroll
    for (int mi = 0; mi < 2; ++mi) {
        const int growo = chunk * 64 + wm * 32 + mi * 16 + lg * 4;
#pragma unroll
        for (int nt = 0; nt < 8; ++nt) {
            const int col = wn * 128 + nt * 16 + lr;
#pragma unroll
            for (int reg = 0; reg < 4; ++reg) {
                const int gr = growo + reg;
                if (gr < ROWS) ob[(size_t)gr * 256 + col] = acc[mi][nt][reg];
            }
        }
    }
}

extern "C" void kernel_launch(void* const* d_in, const int* in_sizes, int n_in,
                              void* d_out, int out_size, void* d_ws, size_t ws_size,
                              hipStream_t stream) {
    const float* h_scores = (const float*)d_in[0];
    const float* v_score  = (const float*)d_in[1];
    const float* h_base   = (const float*)d_in[2];
    const float* v_base   = (const float*)d_in[3];
    float* out = (float*)d_out;
    unsigned short* bm = (unsigned short*)d_ws;   // needs B*64KB = 8MB scratch

    const int B = in_sizes[0] / SCORE_B_STRIDE;   // 128

    bm_build<<<B, 256, 0, stream>>>(h_base, v_base, bm);
    patch_gemm<<<B * NCHUNK, 256, 0, stream>>>(h_scores, v_score, bm, out);
}

// Round 3
// 35.071 us; speedup vs baseline: 5.3098x; 1.0857x over previous
//
#include <hip/hip_runtime.h>

typedef __attribute__((ext_vector_type(8))) short bf16x8;
typedef __attribute__((ext_vector_type(4))) float f32x4;

#define PATCHES 196
#define ROWS 588             // 196 patches * 3 channels
#define NCHUNK 10            // ceil(588/64) row-chunks per batch
#define SCORE_B_STRIDE 5376  // 128*3*14 floats

// pack two f32 -> two bf16 (RNE) in one u32
static __device__ __forceinline__ unsigned f2bf2(float a, float b) {
    union { float f; unsigned u; } x, y; x.f = a; y.f = b;
    unsigned lo = (x.u + 0x7FFFu + ((x.u >> 16) & 1u)) >> 16;
    unsigned hi = (y.u + 0x7FFFu + ((y.u >> 16) & 1u)) & 0xFFFF0000u;
    return lo | hi;
}

// ---------------- Kernel 1: BM workspace, layout [b][k>>3][mn][8k] bf16 -------
// chunk index kc8 = k>>3 (16 per b); uint4 at bmv[((b*16 + kc8)*256) + mn]
// holds BM[k0..k0+7][mn] = v_base[k][m]*h_base[k][n], mn = m*16+n.
__global__ __launch_bounds__(256) void bm_build(
    const float* __restrict__ h_base,   // [B,128,16]
    const float* __restrict__ v_base,   // [B,128,16]
    uint4* __restrict__ bmv)
{
    __shared__ float hbT[16][68];   // [m][k'] pad->stride 68: 2-way conflicts only
    __shared__ float vbT[16][68];
    const int b = blockIdx.x, zb = blockIdx.y, t = threadIdx.x;
    const float* hg = h_base + (size_t)b * 2048 + zb * 1024;
    const float* vg = v_base + (size_t)b * 2048 + zb * 1024;
#pragma unroll
    for (int i = 0; i < 4; ++i) {
        const int idx = t + i * 256;        // 0..1023 -> k' = idx>>4, m = idx&15
        hbT[idx & 15][idx >> 4] = hg[idx];
        vbT[idx & 15][idx >> 4] = vg[idx];
    }
    __syncthreads();

    const int m = t >> 4, n = t & 15;       // mn = t
    uint4* dst = bmv + ((size_t)b * 16 + zb * 8) * 256 + t;
#pragma unroll
    for (int i = 0; i < 8; ++i) {           // local k-chunk, global kc8 = zb*8+i
        const float* vp = &vbT[m][i * 8];   // broadcast across 16-lane groups
        const float* hp = &hbT[n][i * 8];
        float p[8];
#pragma unroll
        for (int j = 0; j < 8; ++j) p[j] = vp[j] * hp[j];
        uint4 u = { f2bf2(p[0],p[1]), f2bf2(p[2],p[3]),
                    f2bf2(p[4],p[5]), f2bf2(p[6],p[7]) };
        dst[i * 256] = u;                   // lanes consecutive -> 1KB coalesced
    }
}

// ---------------- Kernel 2: fused softmax-W (LDS) + MFMA GEMM (B from L2) -----
__global__ __launch_bounds__(256, 3) void patch_gemm(
    const float* __restrict__ h_scores, // [B,128,3,14]
    const float* __restrict__ v_score,  // [B,128,3,14]
    const uint4* __restrict__ bmv,
    float* __restrict__ out)            // [B,588,256]
{
    __shared__ __align__(16) char lds[16384];   // W: 64 rows x 256B, XOR-swizzled

    const int bid = blockIdx.x;
    const int xcd = bid & 7, rest = bid >> 3;   // bijective: b%8 == XCD == k1 writer
    const int b = (rest / NCHUNK) * 8 + xcd;
    const int chunk = rest % NCHUNK;
    const int t = threadIdx.x;

    // ---- softmax weights: thread = (row r = t>>2, k-quarter kq = t&3) ----
    {
        const int r = t >> 2, kq = t & 3;
        const int grow = chunk * 64 + r;
        const int geff = grow < ROWS ? grow : ROWS - 1;  // clamp; masked at store
        const int p = geff / 3, c = geff - p * 3;
        const int np = p / 14, mp = p - np * 14;
        const float* hsb = h_scores + (size_t)b * SCORE_B_STRIDE;
        const float* vsb = v_score  + (size_t)b * SCORE_B_STRIDE;
        const int hix = c * 14 + np, vix = c * 14 + mp;

        float sc[32];
#pragma unroll
        for (int j = 0; j < 32; ++j) {
            const int k = kq * 32 + j;
            sc[j] = hsb[k * 42 + hix] * vsb[k * 42 + vix];
        }
        float mx = sc[0];
#pragma unroll
        for (int j = 1; j < 32; ++j) mx = fmaxf(mx, sc[j]);
        mx = fmaxf(mx, __shfl_xor(mx, 1));
        mx = fmaxf(mx, __shfl_xor(mx, 2));
        float sum = 0.f;
#pragma unroll
        for (int j = 0; j < 32; ++j) { sc[j] = __expf(sc[j] - mx); sum += sc[j]; }
        sum += __shfl_xor(sum, 1);
        sum += __shfl_xor(sum, 2);
        const float inv = 1.f / sum;

        const int sw = (r & 7) << 4;
#pragma unroll
        for (int s2 = 0; s2 < 4; ++s2) {
            const int kpos = (kq * 32 + s2 * 8) * 2;     // byte offset of k0
            uint4 u = { f2bf2(sc[s2*8+0]*inv, sc[s2*8+1]*inv),
                        f2bf2(sc[s2*8+2]*inv, sc[s2*8+3]*inv),
                        f2bf2(sc[s2*8+4]*inv, sc[s2*8+5]*inv),
                        f2bf2(sc[s2*8+6]*inv, sc[s2*8+7]*inv) };
            *(uint4*)(lds + r * 256 + (kpos ^ sw)) = u;
        }
    }
    __syncthreads();

    // ---- MFMA: waves (wm = w>>1, wn = w&1); A from LDS, B from global/L2 ----
    const int w = t >> 6, lane = t & 63;
    const int wm = w >> 1, wn = w & 1;
    const int lr = lane & 15, lg = lane >> 4;

    bf16x8 afrag[2][4];
#pragma unroll
    for (int mi = 0; mi < 2; ++mi) {
        const int r2 = wm * 32 + mi * 16 + lr;
        const int sw = (r2 & 7) << 4;
#pragma unroll
        for (int kc = 0; kc < 4; ++kc)
            afrag[mi][kc] = *(const bf16x8*)(lds + r2 * 256 + ((kc * 64 + lg * 16) ^ sw));
    }

    const uint4* bmb = bmv + (size_t)b * 4096;   // b*16*256

    f32x4 acc[2][8];
#pragma unroll
    for (int mi = 0; mi < 2; ++mi)
#pragma unroll
        for (int nt = 0; nt < 8; ++nt)
            acc[mi][nt] = (f32x4){0.f, 0.f, 0.f, 0.f};

#pragma unroll
    for (int nt = 0; nt < 8; ++nt) {
        const int mn = wn * 128 + nt * 16 + lr;
#pragma unroll
        for (int kc = 0; kc < 4; ++kc) {
            uint4 raw = bmb[(kc * 4 + lg) * 256 + mn];   // 256B-coalesced, L1/L2-hot
            bf16x8 bfrag = *(bf16x8*)&raw;
            acc[0][nt] = __builtin_amdgcn_mfma_f32_16x16x32_bf16(afrag[0][kc], bfrag, acc[0][nt], 0, 0, 0);
            acc[1][nt] = __builtin_amdgcn_mfma_f32_16x16x32_bf16(afrag[1][kc], bfrag, acc[1][nt], 0, 0, 0);
        }
    }

    // ---- store: C/D layout col=lane&15, row=(lane>>4)*4+reg ----
    float* ob = out + (size_t)b * (ROWS * 256);
#pragma unroll
    for (int mi = 0; mi < 2; ++mi) {
        const int growo = chunk * 64 + wm * 32 + mi * 16 + lg * 4;
#pragma unroll
        for (int nt = 0; nt < 8; ++nt) {
            const int col = wn * 128 + nt * 16 + lr;
#pragma unroll
            for (int reg = 0; reg < 4; ++reg) {
                const int gr = growo + reg;
                if (gr < ROWS) ob[(size_t)gr * 256 + col] = acc[mi][nt][reg];
            }
        }
    }
}

extern "C" void kernel_launch(void* const* d_in, const int* in_sizes, int n_in,
                              void* d_out, int out_size, void* d_ws, size_t ws_size,
                              hipStream_t stream) {
    const float* h_scores = (const float*)d_in[0];
    const float* v_score  = (const float*)d_in[1];
    const float* h_base   = (const float*)d_in[2];
    const float* v_base   = (const float*)d_in[3];
    float* out = (float*)d_out;
    uint4* bmv = (uint4*)d_ws;                    // B*64KB = 8MB scratch

    const int B = in_sizes[0] / SCORE_B_STRIDE;   // 128

    bm_build<<<dim3(B, 2), 256, 0, stream>>>(h_base, v_base, bmv);
    patch_gemm<<<B * NCHUNK, 256, 0, stream>>>(h_scores, v_score, bmv, out);
}